// Round 6
// baseline (208.917 us; speedup 1.0000x reference)
//
#include <hip/hip_runtime.h>

// ---------------------------------------------------------------------------
// MHSA bf16-MFMA pipeline v6: B=2, S=2048, D=1024, H=16, HD=64
//   p1: x f32 -> bf16;  p2: W_qkv & W_out transposes -> bf16 [N][K] (fused)
//   k1: qkv GEMM; Q (pre-scaled log2e/8) + K -> qk_bf [4096][2048],
//       V -> vT[bh][d][t] in epilogue
//   k2: flash attention, 2-way t-split (grid z), no-max softmax, partial
//       O (bf16) + l (f32) out;  k2b: merge (O0+O1)/(l0+l1) -> attn_b
//   k3: out GEMM -> f32
// Frag layouts (m89/m91): x32: A[m=l16][k=quad*8+j], B[k=quad*8+j][n=l16];
// x16: A[m=l16][k=quad*4+j], B[k=quad*4+j][n=l16]; C: col=l16, row=quad*4+i.
// ws (64 MB): Wout_t 0-2 | qk_bf 2-18 | vT 18-26 | attn_b 26-34 |
//   x_bf 34-42 (lpart overlays, dead after k1) | Wqkv_t 42-48 | Opart 48-64
// ---------------------------------------------------------------------------

typedef short bf16x8 __attribute__((ext_vector_type(8)));
typedef short bf16x4 __attribute__((ext_vector_type(4)));
typedef float f32x4 __attribute__((ext_vector_type(4)));

#if __has_builtin(__builtin_amdgcn_mfma_f32_16x16x16_bf16)
#define MFMA16(a, b, c) __builtin_amdgcn_mfma_f32_16x16x16_bf16(a, b, c, 0, 0, 0)
#else
#define MFMA16(a, b, c) __builtin_amdgcn_mfma_f32_16x16x16bf16_1k(a, b, c, 0, 0, 0)
#endif

__device__ __forceinline__ unsigned short f2bf(float f) {   // RNE
  unsigned u = __float_as_uint(f);
  u = (u + 0x7fffu + ((u >> 16) & 1u)) >> 16;
  return (unsigned short)u;
}
__device__ __forceinline__ unsigned pack_bf2(float lo, float hi) {
  unsigned a = __float_as_uint(lo) + 0x8000u;
  unsigned b = __float_as_uint(hi) + 0x8000u;
  return __builtin_amdgcn_perm(b, a, 0x07060302);
}
__device__ __forceinline__ float bf_lo(unsigned u) { return __uint_as_float(u << 16); }
__device__ __forceinline__ float bf_hi(unsigned u) { return __uint_as_float(u & 0xffff0000u); }
__device__ __forceinline__ void load_lds16(const unsigned short* g, unsigned short* l) {
  __builtin_amdgcn_global_load_lds(
      (const __attribute__((address_space(1))) void*)g,
      (__attribute__((address_space(3))) void*)l, 16, 0, 0);
}

// --- p1: f32 -> bf16 -------------------------------------------------------
__global__ __launch_bounds__(256) void cvt_f32_bf16(
    const float* __restrict__ in, unsigned short* __restrict__ out, int n)
{
  const int i = (blockIdx.x * 256 + threadIdx.x) * 8;
  if (i >= n) return;
  float4 f0 = *(const float4*)(in + i);
  float4 f1 = *(const float4*)(in + i + 4);
  union { unsigned short u[8]; uint4 v; } pk;
  pk.u[0] = f2bf(f0.x); pk.u[1] = f2bf(f0.y); pk.u[2] = f2bf(f0.z); pk.u[3] = f2bf(f0.w);
  pk.u[4] = f2bf(f1.x); pk.u[5] = f2bf(f1.y); pk.u[6] = f2bf(f1.z); pk.u[7] = f2bf(f1.w);
  *(uint4*)(out + i) = pk.v;
}

// --- p2: fused transpose+cvt for both weights: f32 [R][C] -> bf16 [C][R] ---
__global__ __launch_bounds__(256) void transpose_cvt2(
    const float* __restrict__ in0, unsigned short* __restrict__ out0, int R0, int C0,
    const float* __restrict__ in1, unsigned short* __restrict__ out1, int R1, int C1)
{
  const float* in = (blockIdx.z == 0) ? in0 : in1;
  unsigned short* out = (blockIdx.z == 0) ? out0 : out1;
  const int R = (blockIdx.z == 0) ? R0 : R1;
  const int C = (blockIdx.z == 0) ? C0 : C1;
  const int c0 = blockIdx.x * 64;
  if (c0 >= C) return;
  __shared__ float tile[64][65];
  const int tid = threadIdx.x;
  const int r0 = blockIdx.y * 64;
  {
    const int rr = tid >> 4;
    const int cc = (tid & 15) * 4;
#pragma unroll
    for (int it = 0; it < 4; ++it) {
      float4 f = *(const float4*)&in[(size_t)(r0 + rr + 16 * it) * C + c0 + cc];
      tile[rr + 16 * it][cc + 0] = f.x;
      tile[rr + 16 * it][cc + 1] = f.y;
      tile[rr + 16 * it][cc + 2] = f.z;
      tile[rr + 16 * it][cc + 3] = f.w;
    }
  }
  __syncthreads();
  {
    const int cr = tid >> 2;
    const int rk = (tid & 3) * 16;
    union { unsigned short u[16]; uint4 v[2]; } pk;
#pragma unroll
    for (int j = 0; j < 16; ++j) pk.u[j] = f2bf(tile[rk + j][cr]);
    uint4* dst = (uint4*)&out[(size_t)(c0 + cr) * R + r0 + rk];
    dst[0] = pk.v[0];
    dst[1] = pk.v[1];
  }
}

// --- k1/k3: GEMM C = A[M,K] @ Bt[N,K]^T + bias -----------------------------
// MODE 0: f32 out (ldc = N). MODE 1: bf16: cols<1024 Q (scaled log2e/8) and
// 1024..2047 K into qk_bf stride ldc; cols>=2048 V -> vT[bh][d][t].
template <int MODE>
__global__ __launch_bounds__(256) void gemm_mfma(
    const unsigned short* __restrict__ A,
    const unsigned short* __restrict__ Bt,
    const float* __restrict__ bias,
    void* __restrict__ Cout, unsigned short* __restrict__ vT,
    int M, int N, int K, int ldc)
{
  __shared__ unsigned short As[128][32];
  __shared__ unsigned short Bs[128][32];
  const int tid = threadIdx.x;
  const int wave = tid >> 6, lane = tid & 63;
  const int l16 = lane & 15, quad = lane >> 4;
  const int m0 = blockIdx.y * 128, n0 = blockIdx.x * 128;
  const int wm = (wave & 1) * 64, wn = (wave >> 1) * 64;
  const int lr = lane >> 2;
  const int lc = (lane & 3) * 8;

  f32x4 acc[4][4] = {};

  for (int k0 = 0; k0 < K; k0 += 32) {
    __syncthreads();
    load_lds16(&A [(size_t)(m0 + 16 * wave + lr) * K + k0 + lc],      &As[16 * wave][0]);
    load_lds16(&A [(size_t)(m0 + 64 + 16 * wave + lr) * K + k0 + lc], &As[64 + 16 * wave][0]);
    load_lds16(&Bt[(size_t)(n0 + 16 * wave + lr) * K + k0 + lc],      &Bs[16 * wave][0]);
    load_lds16(&Bt[(size_t)(n0 + 64 + 16 * wave + lr) * K + k0 + lc], &Bs[64 + 16 * wave][0]);
    __syncthreads();

    bf16x8 af[4], bfr[4];
#pragma unroll
    for (int mi = 0; mi < 4; ++mi)
      af[mi] = *(const bf16x8*)&As[wm + 16 * mi + l16][quad * 8];
#pragma unroll
    for (int ni = 0; ni < 4; ++ni)
      bfr[ni] = *(const bf16x8*)&Bs[wn + 16 * ni + l16][quad * 8];
#pragma unroll
    for (int mi = 0; mi < 4; ++mi)
#pragma unroll
      for (int ni = 0; ni < 4; ++ni)
        acc[mi][ni] = __builtin_amdgcn_mfma_f32_16x16x32_bf16(
            af[mi], bfr[ni], acc[mi][ni], 0, 0, 0);
  }

  const float SCQ = 0.18033688f;   // log2(e)/sqrt(64), folded into Q
#pragma unroll
  for (int ni = 0; ni < 4; ++ni) {
    const int colb = n0 + wn + 16 * ni;
    const int col = colb + l16;
    const float bv = bias[col];
    if (MODE == 0) {
#pragma unroll
      for (int mi = 0; mi < 4; ++mi)
#pragma unroll
        for (int i = 0; i < 4; ++i) {
          const int row = m0 + wm + 16 * mi + quad * 4 + i;
          ((float*)Cout)[(size_t)row * ldc + col] = acc[mi][ni][i] + bv;
        }
    } else if (colb < 1024) {          // Q: pre-scale for exp2 softmax
#pragma unroll
      for (int mi = 0; mi < 4; ++mi)
#pragma unroll
        for (int i = 0; i < 4; ++i) {
          const int row = m0 + wm + 16 * mi + quad * 4 + i;
          ((unsigned short*)Cout)[(size_t)row * ldc + col] = f2bf((acc[mi][ni][i] + bv) * SCQ);
        }
    } else if (colb < 2048) {          // K
#pragma unroll
      for (int mi = 0; mi < 4; ++mi)
#pragma unroll
        for (int i = 0; i < 4; ++i) {
          const int row = m0 + wm + 16 * mi + quad * 4 + i;
          ((unsigned short*)Cout)[(size_t)row * ldc + col] = f2bf(acc[mi][ni][i] + bv);
        }
    } else {                           // V -> vT[bh][d][t], packed pairs in t
      const int h = (col - 2048) >> 6, d = col & 63;
#pragma unroll
      for (int mi = 0; mi < 4; ++mi) {
        const int row = m0 + wm + 16 * mi + quad * 4;   // +i, i=0..3
        const int bb = row >> 11, t = row & 2047;
        unsigned short* dst = &vT[((size_t)(bb * 16 + h) * 64 + d) * 2048 + t];
        *(unsigned*)(dst)     = pack_bf2(acc[mi][ni][0] + bv, acc[mi][ni][1] + bv);
        *(unsigned*)(dst + 2) = pack_bf2(acc[mi][ni][2] + bv, acc[mi][ni][3] + bv);
      }
    }
  }
}

// --- k2: flash attention, 2-way t-split ------------------------------------
// Grid (16, 32, 2); block = 4 waves; wave w: q rows [bx*128 + 32w, +32),
// keys [z*1024, +1024) (16 tiles of 64). K,V double-buffered LDS via
// global_load_lds, XOR chunk swizzle. S^T = K Q^T (x32); PV: O^T = V^T P^T
// (x16) register-direct; l via ones-MFMA. Partials out (summable: no-max).
__global__ __launch_bounds__(256, 4) void attn_mfma(
    const unsigned short* __restrict__ qk,    // [4096][2048] (Q|K)
    const unsigned short* __restrict__ vT,    // [32][64][2048]
    unsigned short* __restrict__ Opart,       // [2][4096][1024] bf16
    float* __restrict__ lpart)                // [2][32][2048]
{
  __shared__ unsigned short Ks[2][4096];
  __shared__ unsigned short Vs[2][4096];

  const int tid = threadIdx.x;
  const int wave = tid >> 6, lane = tid & 63;
  const int l16 = lane & 15, quad = lane >> 4;
  const int bh = blockIdx.y, b = bh >> 4, h = bh & 15;
  const int tpar = blockIdx.z;
  const int s0 = blockIdx.x * 128 + wave * 32;

  const unsigned short* qb = qk + (size_t)(b * 2048) * 2048 + h * 64;
  const unsigned short* kb = qb + 1024;
  const unsigned short* vb = vT + (size_t)bh * 64 * 2048;

  const int srow = lane >> 3;                     // 0..7
  const int schunk = ((lane & 7) ^ srow) * 8;     // swizzled 16B chunk
  const int r0a = wave * 16;
  const int tbase = tpar * 1024;
  const unsigned short* kg0 = kb + (size_t)(tbase + r0a + srow) * 2048 + schunk;
  const unsigned short* kg1 = kg0 + (size_t)8 * 2048;
  const unsigned short* vg0 = vb + (size_t)(r0a + srow) * 2048 + tbase + schunk;
  const unsigned short* vg1 = vg0 + (size_t)8 * 2048;

#define STAGE_KV(buf, t0)                                            \
  do {                                                               \
    load_lds16(kg0 + (size_t)(t0) * 2048, &Ks[buf][r0a * 64]);       \
    load_lds16(kg1 + (size_t)(t0) * 2048, &Ks[buf][(r0a + 8) * 64]); \
    load_lds16(vg0 + (t0),                &Vs[buf][r0a * 64]);       \
    load_lds16(vg1 + (t0),                &Vs[buf][(r0a + 8) * 64]); \
  } while (0)

  STAGE_KV(0, 0);

  // Q frags (x32 B-layout: k=d, n=q); Q pre-scaled by log2e/8
  bf16x8 qf[2][2];
#pragma unroll
  for (int mt = 0; mt < 2; ++mt)
#pragma unroll
    for (int ks = 0; ks < 2; ++ks)
      qf[mt][ks] = *(const bf16x8*)&qb[(size_t)(s0 + 16 * mt + l16) * 2048 + 32 * ks + quad * 8];

  f32x4 O[2][4] = {};      // O^T accum: [mt][nd], C col=q=l16, row=d local
  f32x4 lacc[2] = {};      // l via ones-MFMA (rows replicated)
  const bf16x4 ones4 = {(short)0x3F80, (short)0x3F80, (short)0x3F80, (short)0x3F80};
  const int sw = l16 & 7;
  const int h2 = quad >> 1, h1 = (quad & 1) * 4;  // V b64 sub-chunk decomp

  for (int it = 0; it < 16; ++it) {
    const int cur = it & 1;
    __syncthreads();
    if (it < 15) STAGE_KV(1 - cur, (it + 1) * 64);

    // ---- K frags (x32 A-layout: m=t, k=d) from swizzled LDS ----
    bf16x8 kf[4][2];
#pragma unroll
    for (int nt = 0; nt < 4; ++nt) {
      const int rb = (16 * nt + l16) * 64;
      kf[nt][0] = *(const bf16x8*)&Ks[cur][rb + ((quad ^ sw) * 8)];
      kf[nt][1] = *(const bf16x8*)&Ks[cur][rb + (((4 + quad) ^ sw) * 8)];
    }

    // ---- V frags (x16 A-layout: m=d, k=t chunk c) ----
    bf16x4 vf[4][4];
#pragma unroll
    for (int nd = 0; nd < 4; ++nd) {
      const int rb = (16 * nd + l16) * 64;
#pragma unroll
      for (int c = 0; c < 4; ++c)
        vf[nd][c] = *(const bf16x4*)&Vs[cur][rb + (((2 * c + h2) ^ sw) * 8 + h1)];
    }

    // ---- S^T = K Q^T (x32): C row=t=quad*4+i, col=q=l16 ----
    f32x4 sf[4][2];
#pragma unroll
    for (int nt = 0; nt < 4; ++nt)
#pragma unroll
      for (int mt = 0; mt < 2; ++mt) {
        f32x4 c = {0.0f, 0.0f, 0.0f, 0.0f};
        c = __builtin_amdgcn_mfma_f32_16x16x32_bf16(kf[nt][0], qf[mt][0], c, 0, 0, 0);
        c = __builtin_amdgcn_mfma_f32_16x16x32_bf16(kf[nt][1], qf[mt][1], c, 0, 0, 0);
        sf[nt][mt] = c;
      }

    // ---- p = exp2(s); pack to x16 B-frags (C-layout == B-frag identity) ----
    bf16x4 pp[2][4];
#pragma unroll
    for (int mt = 0; mt < 2; ++mt)
#pragma unroll
      for (int nt = 0; nt < 4; ++nt) {
        const float p0 = __builtin_amdgcn_exp2f(sf[nt][mt][0]);
        const float p1 = __builtin_amdgcn_exp2f(sf[nt][mt][1]);
        const float p2 = __builtin_amdgcn_exp2f(sf[nt][mt][2]);
        const float p3 = __builtin_amdgcn_exp2f(sf[nt][mt][3]);
        uint2 w;
        w.x = pack_bf2(p0, p1);
        w.y = pack_bf2(p2, p3);
        pp[mt][nt] = *(bf16x4*)&w;
      }

    // ---- O^T += V^T P^T (x16); l += ones P^T ----
#pragma unroll
    for (int c = 0; c < 4; ++c)
#pragma unroll
      for (int mt = 0; mt < 2; ++mt) {
        lacc[mt] = MFMA16(ones4, pp[mt][c], lacc[mt]);
#pragma unroll
        for (int nd = 0; nd < 4; ++nd)
          O[mt][nd] = MFMA16(vf[nd][c], pp[mt][c], O[mt][nd]);
      }
  }

  // ---- epilogue: store partial O (bf16) + partial l (f32) ----
#pragma unroll
  for (int mt = 0; mt < 2; ++mt) {
    const size_t row = (size_t)(b * 2048 + s0 + 16 * mt + l16);
    unsigned short* dst = &Opart[((size_t)tpar * 4096 + row) * 1024 + h * 64];
#pragma unroll
    for (int nd = 0; nd < 4; ++nd) {
      uint2 w;
      w.x = pack_bf2(O[mt][nd][0], O[mt][nd][1]);
      w.y = pack_bf2(O[mt][nd][2], O[mt][nd][3]);
      *(uint2*)&dst[16 * nd + quad * 4] = w;
    }
    if (quad == 0)
      lpart[((size_t)tpar * 32 + bh) * 2048 + s0 + 16 * mt + l16] = lacc[mt][0];
  }
#undef STAGE_KV
}

// --- k2b: merge t-split partials ------------------------------------------
__global__ __launch_bounds__(256) void attn_merge(
    const unsigned short* __restrict__ Opart,   // [2][4096][1024] bf16
    const float* __restrict__ lpart,            // [2][32][2048]
    unsigned short* __restrict__ attn_out)      // [4096][1024]
{
  const int row = blockIdx.x;                   // 0..4095
  const int c0 = threadIdx.x * 4;
  const int b = row >> 11, s = row & 2047;
  const int h = c0 >> 6;
  const size_t li = (size_t)(b * 16 + h) * 2048 + s;
  const float inv = 1.0f / (lpart[li] + lpart[65536 + li]);
  const size_t oi = (size_t)row * 1024 + c0;
  uint2 o0 = *(const uint2*)&Opart[oi];
  uint2 o1 = *(const uint2*)&Opart[4194304 + oi];
  uint2 w;
  w.x = pack_bf2((bf_lo(o0.x) + bf_lo(o1.x)) * inv, (bf_hi(o0.x) + bf_hi(o1.x)) * inv);
  w.y = pack_bf2((bf_lo(o0.y) + bf_lo(o1.y)) * inv, (bf_hi(o0.y) + bf_hi(o1.y)) * inv);
  *(uint2*)&attn_out[oi] = w;
}

extern "C" void kernel_launch(void* const* d_in, const int* in_sizes, int n_in,
                              void* d_out, int out_size, void* d_ws, size_t ws_size,
                              hipStream_t stream) {
  const float* x     = (const float*)d_in[0];
  const float* W_qkv = (const float*)d_in[1];
  const float* b_qkv = (const float*)d_in[2];
  const float* W_out = (const float*)d_in[3];
  const float* b_out = (const float*)d_in[4];
  float* out = (float*)d_out;

  char* ws = (char*)d_ws;
  const size_t MB = 1048576;
  unsigned short* Wout_t = (unsigned short*)(ws);             //  0-2 MB
  unsigned short* qk_bf  = (unsigned short*)(ws + 2 * MB);    //  2-18 MB
  unsigned short* vT     = (unsigned short*)(ws + 18 * MB);   // 18-26 MB
  unsigned short* attn_b = (unsigned short*)(ws + 26 * MB);   // 26-34 MB
  unsigned short* x_bf   = (unsigned short*)(ws + 34 * MB);   // 34-42 MB (dead after k1)
  float*          lpart  = (float*)(ws + 34 * MB);            // overlays x_bf
  unsigned short* Wqkv_t = (unsigned short*)(ws + 42 * MB);   // 42-48 MB
  unsigned short* Opart  = (unsigned short*)(ws + 48 * MB);   // 48-64 MB

  cvt_f32_bf16<<<2048, 256, 0, stream>>>(x, x_bf, 4096 * 1024);
  transpose_cvt2<<<dim3(48, 16, 2), 256, 0, stream>>>(
      W_qkv, Wqkv_t, 1024, 3072, W_out, Wout_t, 1024, 1024);

  gemm_mfma<1><<<dim3(24, 32), 256, 0, stream>>>(x_bf, Wqkv_t, b_qkv, qk_bf, vT,
                                                 4096, 3072, 1024, 2048);
  attn_mfma<<<dim3(16, 32, 2), 256, 0, stream>>>(qk_bf, vT, Opart, lpart);
  attn_merge<<<4096, 256, 0, stream>>>(Opart, lpart, attn_b);
  gemm_mfma<0><<<dim3(8, 32), 256, 0, stream>>>(attn_b, Wout_t, b_out, out, nullptr,
                                                4096, 1024, 1024, 1024);
}

// Round 7
// 196.009 us; speedup vs baseline: 1.0659x; 1.0659x over previous
//
#include <hip/hip_runtime.h>

// ---------------------------------------------------------------------------
// MHSA bf16-MFMA pipeline v7: B=2, S=2048, D=1024, H=16, HD=64
//   p:  fused prep (z=0: W_qkv^T, z=1: W_out^T, z=2: x f32->bf16)
//   k1: qkv GEMM (global_load_lds staging); Q (pre-scaled log2e/8) + K ->
//       qk_bf [4096][2048]; V -> vT[bh][d][t] in epilogue
//   k2: flash attention, reg->LDS staged K/V double buffer (NO vmcnt drain
//       at barriers: loads land in VGPRs one iter ahead, barrier = lgkm only),
//       S^T via 16x16x32, PV register-direct via 16x16x16, l via ones-MFMA
//   k3: out GEMM -> f32
// Frag layouts (m89/m91): x32: A[m=l16][k=quad*8+j], B[k=quad*8+j][n=l16];
// x16: A[m=l16][k=quad*4+j], B[k=quad*4+j][n=l16]; C: col=l16, row=quad*4+i.
// ws (48 MB): Wout_t 0-2 | qk_bf 2-18 | vT 18-26 | attn_b 26-34 |
//             x_bf 34-42 | Wqkv_t 42-48
// ---------------------------------------------------------------------------

typedef short bf16x8 __attribute__((ext_vector_type(8)));
typedef short bf16x4 __attribute__((ext_vector_type(4)));
typedef float f32x4 __attribute__((ext_vector_type(4)));

#if __has_builtin(__builtin_amdgcn_mfma_f32_16x16x16_bf16)
#define MFMA16(a, b, c) __builtin_amdgcn_mfma_f32_16x16x16_bf16(a, b, c, 0, 0, 0)
#else
#define MFMA16(a, b, c) __builtin_amdgcn_mfma_f32_16x16x16bf16_1k(a, b, c, 0, 0, 0)
#endif

__device__ __forceinline__ unsigned short f2bf(float f) {   // RNE
  unsigned u = __float_as_uint(f);
  u = (u + 0x7fffu + ((u >> 16) & 1u)) >> 16;
  return (unsigned short)u;
}
__device__ __forceinline__ unsigned pack_bf2(float lo, float hi) {
  unsigned a = __float_as_uint(lo) + 0x8000u;
  unsigned b = __float_as_uint(hi) + 0x8000u;
  return __builtin_amdgcn_perm(b, a, 0x07060302);
}
__device__ __forceinline__ void load_lds16(const unsigned short* g, unsigned short* l) {
  __builtin_amdgcn_global_load_lds(
      (const __attribute__((address_space(1))) void*)g,
      (__attribute__((address_space(3))) void*)l, 16, 0, 0);
}

// --- p: fused prep ---------------------------------------------------------
// z=0: W_qkv [1024,3072] -> Wqkv_t [3072,1024] bf16 (grid x=48,y=16)
// z=1: W_out [1024,1024] -> Wout_t [1024,1024] bf16 (x<16 active)
// z=2: x f32 -> bf16, grid-stride over 4096*1024 elems
__global__ __launch_bounds__(256) void prep(
    const float* __restrict__ x, unsigned short* __restrict__ x_bf,
    const float* __restrict__ W_qkv, unsigned short* __restrict__ Wqkv_t,
    const float* __restrict__ W_out, unsigned short* __restrict__ Wout_t)
{
  const int tid = threadIdx.x;
  if (blockIdx.z == 2) {
    const int bid = blockIdx.y * 48 + blockIdx.x;          // 0..767
    const int n = 4096 * 1024;
    for (int i = bid * 2048 + tid * 8; i < n; i += 768 * 2048) {
      float4 f0 = *(const float4*)(x + i);
      float4 f1 = *(const float4*)(x + i + 4);
      union { unsigned short u[8]; uint4 v; } pk;
      pk.u[0] = f2bf(f0.x); pk.u[1] = f2bf(f0.y); pk.u[2] = f2bf(f0.z); pk.u[3] = f2bf(f0.w);
      pk.u[4] = f2bf(f1.x); pk.u[5] = f2bf(f1.y); pk.u[6] = f2bf(f1.z); pk.u[7] = f2bf(f1.w);
      *(uint4*)(x_bf + i) = pk.v;
    }
    return;
  }
  const float* in = (blockIdx.z == 0) ? W_qkv : W_out;
  unsigned short* out = (blockIdx.z == 0) ? Wqkv_t : Wout_t;
  const int R = 1024;
  const int C = (blockIdx.z == 0) ? 3072 : 1024;
  const int c0 = blockIdx.x * 64;
  if (c0 >= C) return;
  __shared__ float tile[64][65];
  const int r0 = blockIdx.y * 64;
  {
    const int rr = tid >> 4;
    const int cc = (tid & 15) * 4;
#pragma unroll
    for (int it = 0; it < 4; ++it) {
      float4 f = *(const float4*)&in[(size_t)(r0 + rr + 16 * it) * C + c0 + cc];
      tile[rr + 16 * it][cc + 0] = f.x;
      tile[rr + 16 * it][cc + 1] = f.y;
      tile[rr + 16 * it][cc + 2] = f.z;
      tile[rr + 16 * it][cc + 3] = f.w;
    }
  }
  __syncthreads();
  {
    const int cr = tid >> 2;
    const int rk = (tid & 3) * 16;
    union { unsigned short u[16]; uint4 v[2]; } pk;
#pragma unroll
    for (int j = 0; j < 16; ++j) pk.u[j] = f2bf(tile[rk + j][cr]);
    uint4* dst = (uint4*)&out[(size_t)(c0 + cr) * R + r0 + rk];
    dst[0] = pk.v[0];
    dst[1] = pk.v[1];
  }
}

// --- k1/k3: GEMM C = A[M,K] @ Bt[N,K]^T + bias -----------------------------
// MODE 0: f32 out (ldc = N). MODE 1: bf16: cols<1024 Q (scaled log2e/8) and
// 1024..2047 K into qk_bf stride ldc; cols>=2048 V -> vT[bh][d][t].
template <int MODE>
__global__ __launch_bounds__(256) void gemm_mfma(
    const unsigned short* __restrict__ A,
    const unsigned short* __restrict__ Bt,
    const float* __restrict__ bias,
    void* __restrict__ Cout, unsigned short* __restrict__ vT,
    int M, int N, int K, int ldc)
{
  __shared__ unsigned short As[128][32];
  __shared__ unsigned short Bs[128][32];
  const int tid = threadIdx.x;
  const int wave = tid >> 6, lane = tid & 63;
  const int l16 = lane & 15, quad = lane >> 4;
  const int m0 = blockIdx.y * 128, n0 = blockIdx.x * 128;
  const int wm = (wave & 1) * 64, wn = (wave >> 1) * 64;
  const int lr = lane >> 2;
  const int lc = (lane & 3) * 8;

  f32x4 acc[4][4] = {};

  for (int k0 = 0; k0 < K; k0 += 32) {
    __syncthreads();
    load_lds16(&A [(size_t)(m0 + 16 * wave + lr) * K + k0 + lc],      &As[16 * wave][0]);
    load_lds16(&A [(size_t)(m0 + 64 + 16 * wave + lr) * K + k0 + lc], &As[64 + 16 * wave][0]);
    load_lds16(&Bt[(size_t)(n0 + 16 * wave + lr) * K + k0 + lc],      &Bs[16 * wave][0]);
    load_lds16(&Bt[(size_t)(n0 + 64 + 16 * wave + lr) * K + k0 + lc], &Bs[64 + 16 * wave][0]);
    __syncthreads();

    bf16x8 af[4], bfr[4];
#pragma unroll
    for (int mi = 0; mi < 4; ++mi)
      af[mi] = *(const bf16x8*)&As[wm + 16 * mi + l16][quad * 8];
#pragma unroll
    for (int ni = 0; ni < 4; ++ni)
      bfr[ni] = *(const bf16x8*)&Bs[wn + 16 * ni + l16][quad * 8];
#pragma unroll
    for (int mi = 0; mi < 4; ++mi)
#pragma unroll
      for (int ni = 0; ni < 4; ++ni)
        acc[mi][ni] = __builtin_amdgcn_mfma_f32_16x16x32_bf16(
            af[mi], bfr[ni], acc[mi][ni], 0, 0, 0);
  }

  const float SCQ = 0.18033688f;   // log2(e)/sqrt(64), folded into Q
#pragma unroll
  for (int ni = 0; ni < 4; ++ni) {
    const int colb = n0 + wn + 16 * ni;
    const int col = colb + l16;
    const float bv = bias[col];
    if (MODE == 0) {
#pragma unroll
      for (int mi = 0; mi < 4; ++mi)
#pragma unroll
        for (int i = 0; i < 4; ++i) {
          const int row = m0 + wm + 16 * mi + quad * 4 + i;
          ((float*)Cout)[(size_t)row * ldc + col] = acc[mi][ni][i] + bv;
        }
    } else if (colb < 1024) {          // Q: pre-scale for exp2 softmax
#pragma unroll
      for (int mi = 0; mi < 4; ++mi)
#pragma unroll
        for (int i = 0; i < 4; ++i) {
          const int row = m0 + wm + 16 * mi + quad * 4 + i;
          ((unsigned short*)Cout)[(size_t)row * ldc + col] = f2bf((acc[mi][ni][i] + bv) * SCQ);
        }
    } else if (colb < 2048) {          // K
#pragma unroll
      for (int mi = 0; mi < 4; ++mi)
#pragma unroll
        for (int i = 0; i < 4; ++i) {
          const int row = m0 + wm + 16 * mi + quad * 4 + i;
          ((unsigned short*)Cout)[(size_t)row * ldc + col] = f2bf(acc[mi][ni][i] + bv);
        }
    } else {                           // V -> vT[bh][d][t], packed pairs in t
      const int h = (col - 2048) >> 6, d = col & 63;
#pragma unroll
      for (int mi = 0; mi < 4; ++mi) {
        const int row = m0 + wm + 16 * mi + quad * 4;   // +i, i=0..3
        const int bb = row >> 11, t = row & 2047;
        unsigned short* dst = &vT[((size_t)(bb * 16 + h) * 64 + d) * 2048 + t];
        *(unsigned*)(dst)     = pack_bf2(acc[mi][ni][0] + bv, acc[mi][ni][1] + bv);
        *(unsigned*)(dst + 2) = pack_bf2(acc[mi][ni][2] + bv, acc[mi][ni][3] + bv);
      }
    }
  }
}

// --- k2: flash attention, reg->LDS staged K/V ------------------------------
// Block = 4 waves; wave w: q rows [bx*128 + 32w, +32), all 2048 keys.
// K,V tiles (64x64 bf16) double-buffered in LDS; staging goes global->VGPR
// (issued one iter ahead; compiler pipelines vmcnt) -> ds_write, so the
// per-iter barrier drains only lgkmcnt (no global drain). XOR chunk swizzle
// (chunk c of row r at c ^ (r&7)). S^T = K Q^T (x32); PV: O^T = V^T P^T
// (x16) with P register-direct (C-of-S^T == x16 B-frag); l via ones-MFMA.
__global__ __launch_bounds__(256, 2) void attn_mfma(
    const unsigned short* __restrict__ qk,    // [4096][2048] (Q|K)
    const unsigned short* __restrict__ vT,    // [32][64][2048]
    unsigned short* __restrict__ attn_out)    // [4096][1024]
{
  __shared__ unsigned short Ks[2][4096];
  __shared__ unsigned short Vs[2][4096];

  const int tid = threadIdx.x;
  const int wave = tid >> 6, lane = tid & 63;
  const int l16 = lane & 15, quad = lane >> 4;
  const int bh = blockIdx.y, b = bh >> 4, h = bh & 15;
  const int s0 = blockIdx.x * 128 + wave * 32;

  const unsigned short* qb = qk + (size_t)(b * 2048) * 2048 + h * 64;
  const unsigned short* kb = qb + 1024;
  const unsigned short* vb = vT + (size_t)bh * 64 * 2048;

  // staging geometry (16B per lane, swizzled chunks)
  const int srow = lane >> 3;                     // 0..7
  const int schunk = ((lane & 7) ^ srow) * 8;     // swizzled 16B chunk
  const int r0a = wave * 16;
  const unsigned short* kg0 = kb + (size_t)(r0a + srow) * 2048 + schunk;
  const unsigned short* kg1 = kg0 + (size_t)8 * 2048;
  const unsigned short* vg0 = vb + (size_t)(r0a + srow) * 2048 + schunk;
  const unsigned short* vg1 = vg0 + (size_t)8 * 2048;
  const int wd0 = r0a * 64 + lane * 8;            // LDS dst (shorts)
  const int wd1 = (r0a + 8) * 64 + lane * 8;

  // tile 0 -> buf 0; tile 1 into regs (in flight across first compute)
  uint4 kr0 = *(const uint4*)(kg0);
  uint4 kr1 = *(const uint4*)(kg1);
  uint4 vr0 = *(const uint4*)(vg0);
  uint4 vr1 = *(const uint4*)(vg1);
  *(uint4*)&Ks[0][wd0] = kr0;  *(uint4*)&Ks[0][wd1] = kr1;
  *(uint4*)&Vs[0][wd0] = vr0;  *(uint4*)&Vs[0][wd1] = vr1;
  kr0 = *(const uint4*)(kg0 + (size_t)64 * 2048);
  kr1 = *(const uint4*)(kg1 + (size_t)64 * 2048);
  vr0 = *(const uint4*)(vg0 + 64);
  vr1 = *(const uint4*)(vg1 + 64);

  // Q frags (x32 B-layout: k=d, n=q); Q pre-scaled by log2e/8
  bf16x8 qf[2][2];
#pragma unroll
  for (int mt = 0; mt < 2; ++mt)
#pragma unroll
    for (int ks = 0; ks < 2; ++ks)
      qf[mt][ks] = *(const bf16x8*)&qb[(size_t)(s0 + 16 * mt + l16) * 2048 + 32 * ks + quad * 8];

  f32x4 O[2][4] = {};      // O^T accum: [mt][nd], C col=q=l16, row=d local
  f32x4 lacc[2] = {};      // l via ones-MFMA (rows replicated)
  const bf16x4 ones4 = {(short)0x3F80, (short)0x3F80, (short)0x3F80, (short)0x3F80};
  const int sw = l16 & 7;
  const int h2 = quad >> 1, h1 = (quad & 1) * 4;  // V b64 sub-chunk decomp

  __syncthreads();

  for (int it = 0; it < 32; ++it) {
    const int cur = it & 1;

    // ---- K frags (x32 A-layout: m=t, k=d) from swizzled LDS ----
    bf16x8 kf[4][2];
#pragma unroll
    for (int nt = 0; nt < 4; ++nt) {
      const int rb = (16 * nt + l16) * 64;
      kf[nt][0] = *(const bf16x8*)&Ks[cur][rb + ((quad ^ sw) * 8)];
      kf[nt][1] = *(const bf16x8*)&Ks[cur][rb + (((4 + quad) ^ sw) * 8)];
    }

    // ---- S^T = K Q^T (x32): C row=t=quad*4+i, col=q=l16 ----
    f32x4 sf[4][2];
#pragma unroll
    for (int nt = 0; nt < 4; ++nt)
#pragma unroll
      for (int mt = 0; mt < 2; ++mt) {
        f32x4 c = {0.0f, 0.0f, 0.0f, 0.0f};
        c = __builtin_amdgcn_mfma_f32_16x16x32_bf16(kf[nt][0], qf[mt][0], c, 0, 0, 0);
        c = __builtin_amdgcn_mfma_f32_16x16x32_bf16(kf[nt][1], qf[mt][1], c, 0, 0, 0);
        sf[nt][mt] = c;
      }

    // ---- stage tile it+1 (regs -> other buffer); prefetch tile it+2 ----
    if (it < 31) {
      *(uint4*)&Ks[cur ^ 1][wd0] = kr0;
      *(uint4*)&Ks[cur ^ 1][wd1] = kr1;
      *(uint4*)&Vs[cur ^ 1][wd0] = vr0;
      *(uint4*)&Vs[cur ^ 1][wd1] = vr1;
      if (it < 30) {
        const size_t ko = (size_t)(it + 2) * 64 * 2048;
        kr0 = *(const uint4*)(kg0 + ko);
        kr1 = *(const uint4*)(kg1 + ko);
        vr0 = *(const uint4*)(vg0 + (it + 2) * 64);
        vr1 = *(const uint4*)(vg1 + (it + 2) * 64);
      }
    }

    // ---- V frags (x16 A-layout: m=d, k=t chunk c) ----
    bf16x4 vf[4][4];
#pragma unroll
    for (int nd = 0; nd < 4; ++nd) {
      const int rb = (16 * nd + l16) * 64;
#pragma unroll
      for (int c = 0; c < 4; ++c)
        vf[nd][c] = *(const bf16x4*)&Vs[cur][rb + (((2 * c + h2) ^ sw) * 8 + h1)];
    }

    // ---- p = exp2(s); pack to x16 B-frags (C-layout == B-frag identity) ----
    bf16x4 pp[2][4];
#pragma unroll
    for (int mt = 0; mt < 2; ++mt)
#pragma unroll
      for (int nt = 0; nt < 4; ++nt) {
        const float p0 = __builtin_amdgcn_exp2f(sf[nt][mt][0]);
        const float p1 = __builtin_amdgcn_exp2f(sf[nt][mt][1]);
        const float p2 = __builtin_amdgcn_exp2f(sf[nt][mt][2]);
        const float p3 = __builtin_amdgcn_exp2f(sf[nt][mt][3]);
        uint2 w;
        w.x = pack_bf2(p0, p1);
        w.y = pack_bf2(p2, p3);
        pp[mt][nt] = *(bf16x4*)&w;
      }

    // ---- O^T += V^T P^T (x16); l += ones P^T ----
#pragma unroll
    for (int c = 0; c < 4; ++c)
#pragma unroll
      for (int mt = 0; mt < 2; ++mt) {
        lacc[mt] = MFMA16(ones4, pp[mt][c], lacc[mt]);
#pragma unroll
        for (int nd = 0; nd < 4; ++nd)
          O[mt][nd] = MFMA16(vf[nd][c], pp[mt][c], O[mt][nd]);
      }

    __syncthreads();
  }

  // ---- epilogue: lane holds q=s0+16mt+l16, d=16nd+quad*4+{0..3} ----
#pragma unroll
  for (int mt = 0; mt < 2; ++mt) {
    const float inv = 1.0f / lacc[mt][0];
    const size_t row = (size_t)(b * 2048 + s0 + 16 * mt + l16);
#pragma unroll
    for (int nd = 0; nd < 4; ++nd) {
      uint2 w;
      w.x = pack_bf2(O[mt][nd][0] * inv, O[mt][nd][1] * inv);
      w.y = pack_bf2(O[mt][nd][2] * inv, O[mt][nd][3] * inv);
      *(uint2*)&attn_out[row * 1024 + h * 64 + 16 * nd + quad * 4] = w;
    }
  }
}

extern "C" void kernel_launch(void* const* d_in, const int* in_sizes, int n_in,
                              void* d_out, int out_size, void* d_ws, size_t ws_size,
                              hipStream_t stream) {
  const float* x     = (const float*)d_in[0];
  const float* W_qkv = (const float*)d_in[1];
  const float* b_qkv = (const float*)d_in[2];
  const float* W_out = (const float*)d_in[3];
  const float* b_out = (const float*)d_in[4];
  float* out = (float*)d_out;

  char* ws = (char*)d_ws;
  const size_t MB = 1048576;
  unsigned short* Wout_t = (unsigned short*)(ws);             //  0-2 MB
  unsigned short* qk_bf  = (unsigned short*)(ws + 2 * MB);    //  2-18 MB
  unsigned short* vT     = (unsigned short*)(ws + 18 * MB);   // 18-26 MB
  unsigned short* attn_b = (unsigned short*)(ws + 26 * MB);   // 26-34 MB
  unsigned short* x_bf   = (unsigned short*)(ws + 34 * MB);   // 34-42 MB
  unsigned short* Wqkv_t = (unsigned short*)(ws + 42 * MB);   // 42-48 MB

  prep<<<dim3(48, 16, 3), 256, 0, stream>>>(x, x_bf, W_qkv, Wqkv_t, W_out, Wout_t);

  gemm_mfma<1><<<dim3(24, 32), 256, 0, stream>>>(x_bf, Wqkv_t, b_qkv, qk_bf, vT,
                                                 4096, 3072, 1024, 2048);
  attn_mfma<<<dim3(16, 32), 256, 0, stream>>>(qk_bf, vT, attn_b);
  gemm_mfma<0><<<dim3(8, 32), 256, 0, stream>>>(attn_b, Wout_t, b_out, out, nullptr,
                                                4096, 1024, 1024, 1024);
}